// Round 1
// baseline (1135.124 us; speedup 1.0000x reference)
//
#include <hip/hip_runtime.h>

typedef short short8  __attribute__((ext_vector_type(8)));
typedef short short4v __attribute__((ext_vector_type(4)));
typedef float f32x4   __attribute__((ext_vector_type(4)));

#define B_   2
#define T_   2048
#define D_   4096
#define N_   32
#define KH_  8
#define H_   128
#define BT_  (B_*T_)
#define NH_  (N_*H_)

__device__ __forceinline__ short f2bf(float f) {
    unsigned u = __float_as_uint(f);
    u += 0x7fffu + ((u >> 16) & 1u);
    return (short)(u >> 16);
}

// global -> LDS async 16B copy; LDS dest = wave-uniform base + lane*16
__device__ __forceinline__ void gl_lds16(const short* g, short* l) {
    __builtin_amdgcn_global_load_lds(
        (const __attribute__((address_space(1))) void*)(g),
        (__attribute__((address_space(3))) void*)(l), 16, 0, 0);
}

// ---------------------------------------------------------------------------
// x fp32 -> bf16 flat cast
// ---------------------------------------------------------------------------
__global__ __launch_bounds__(256) void cast_x_kernel(const float* __restrict__ in,
                                                     short* __restrict__ out) {
    const size_t i = ((size_t)blockIdx.x * 256 + threadIdx.x) * 8;
    float4 v0 = *reinterpret_cast<const float4*>(in + i);
    float4 v1 = *reinterpret_cast<const float4*>(in + i + 4);
    short8 s;
    s[0] = f2bf(v0.x); s[1] = f2bf(v0.y); s[2] = f2bf(v0.z); s[3] = f2bf(v0.w);
    s[4] = f2bf(v1.x); s[5] = f2bf(v1.y); s[6] = f2bf(v1.z); s[7] = f2bf(v1.w);
    *reinterpret_cast<short8*>(out + i) = s;
}

// ---------------------------------------------------------------------------
// Transpose + cast: in (R,C) fp32 slices -> out (C,R) bf16 slices
// ---------------------------------------------------------------------------
__global__ void transpose_cast_kernel(const float* __restrict__ in,
                                      short* __restrict__ out, int R, int C) {
    __shared__ float tile[32][33];
    const long long slice = blockIdx.z;
    in  += slice * (long long)R * C;
    out += slice * (long long)R * C;
    const int c0 = blockIdx.x * 32, r0 = blockIdx.y * 32;
    const int tx = threadIdx.x, ty = threadIdx.y;
#pragma unroll
    for (int i = 0; i < 4; i++) {
        int r = r0 + ty + i * 8;
        tile[ty + i * 8][tx] = in[(long long)r * C + c0 + tx];
    }
    __syncthreads();
#pragma unroll
    for (int i = 0; i < 4; i++) {
        int cc = c0 + ty + i * 8;
        out[(long long)cc * R + r0 + tx] = f2bf(tile[tx][ty + i * 8]);
    }
}

// ---------------------------------------------------------------------------
// QKV projection GEMM (global_load_lds staging), fused RoPE epilogue.
// Outputs: q (B,N,T,H), k (B,KH,T,H)  [per-head dense], vt (B,KH,H,T).
// ---------------------------------------------------------------------------
__global__ __launch_bounds__(256) void qkv_gemm_kernel(
    const short* __restrict__ xb, const int* __restrict__ positions,
    const short* __restrict__ wqt, const short* __restrict__ wkvt,
    short* __restrict__ qo, short* __restrict__ ko, short* __restrict__ vto)
{
    __shared__ short As[128 * 32];
    __shared__ short Bs[128 * 32];
    const int hb  = blockIdx.x;
    const int m0  = blockIdx.y * 128;
    const int tid = threadIdx.x;
    const int w = tid >> 6, lane = tid & 63;
    const int quad = lane >> 4, l15 = lane & 15;
    const int arow = lane >> 2, aslot = lane & 3;

    const short* Bbase = (hb < 32) ? (wqt + (size_t)hb * H_ * D_)
                                   : (wkvt + (size_t)(hb - 32) * H_ * D_);

    f32x4 acc[2][8];
    const f32x4 zero4 = {0.f, 0.f, 0.f, 0.f};
#pragma unroll
    for (int jr = 0; jr < 2; jr++)
#pragma unroll
        for (int jc = 0; jc < 8; jc++) acc[jr][jc] = zero4;

    for (int kt = 0; kt < D_ / 32; kt++) {
        const int kk0 = kt * 32;
        __syncthreads();
#pragma unroll
        for (int i = 0; i < 2; i++) {
            const int ci = 2 * w + i;
            const int row = ci * 16 + arow;
            const int sl = aslot ^ (row & 3);
            gl_lds16(xb + (size_t)(m0 + row) * D_ + kk0 + sl * 8, &As[ci * 512]);
            gl_lds16(Bbase + (size_t)row * D_ + kk0 + sl * 8, &Bs[ci * 512]);
        }
        __syncthreads();
        short8 a[2], bq[8];
        const int fs = (quad ^ (l15 & 3)) * 8;
#pragma unroll
        for (int jr = 0; jr < 2; jr++)
            a[jr] = *reinterpret_cast<const short8*>(&As[(32 * w + 16 * jr + l15) * 32 + fs]);
#pragma unroll
        for (int jc = 0; jc < 8; jc++)
            bq[jc] = *reinterpret_cast<const short8*>(&Bs[(16 * jc + l15) * 32 + fs]);
#pragma unroll
        for (int jr = 0; jr < 2; jr++)
#pragma unroll
            for (int jc = 0; jc < 8; jc++)
                acc[jr][jc] = __builtin_amdgcn_mfma_f32_16x16x32_bf16(a[jr], bq[jc], acc[jr][jc], 0, 0, 0);
    }

    if (hb < 40) {
        // q or k: RoPE; q pre-scaled by H^-0.5 * log2e (fixed-max softmax)
        short* hd; float qs;
        if (hb < 32) { qs = 0.08838834764831845f * 1.4426950408889634f; }
        else         { qs = 1.0f; }
#pragma unroll
        for (int jr = 0; jr < 2; jr++) {
#pragma unroll
            for (int reg = 0; reg < 4; reg++) {
                const int bt = m0 + 32 * w + 16 * jr + quad * 4 + reg;
                const int b = bt >> 11, t = bt & (T_ - 1);
                short* dst = (hb < 32)
                    ? qo + ((size_t)(b * N_ + hb) * T_ + t) * H_
                    : ko + ((size_t)(b * KH_ + (hb - 32)) * T_ + t) * H_;
                const float pos = (float)positions[bt];
#pragma unroll
                for (int jc = 0; jc < 4; jc++) {
                    const int h2 = 16 * jc + l15;
                    float inv_ts = exp2f((float)h2 * -0.20762050593048935f); // log2(10000)/64
                    float rev = pos * inv_ts * 0.15915494309189535f;
                    rev -= floorf(rev);
                    float sn, cs;
                    __sincosf(rev * 6.283185307179586f, &sn, &cs);
                    float x1 = acc[jr][jc][reg], x2 = acc[jr][jc + 4][reg];
                    dst[h2]      = f2bf((x1 * cs - x2 * sn) * qs);
                    dst[h2 + 64] = f2bf((x2 * cs + x1 * sn) * qs);
                }
            }
        }
    } else {
        // v: store transposed (B,KH,H,T)
        const int vh = hb - 40;
        const int b = m0 >> 11;
#pragma unroll
        for (int jr = 0; jr < 2; jr++) {
            const int t0r = (m0 - b * T_) + 32 * w + 16 * jr + quad * 4;
#pragma unroll
            for (int jc = 0; jc < 8; jc++) {
                const int h = 16 * jc + l15;
                short4v pv;
                pv[0] = f2bf(acc[jr][jc][0]); pv[1] = f2bf(acc[jr][jc][1]);
                pv[2] = f2bf(acc[jr][jc][2]); pv[3] = f2bf(acc[jr][jc][3]);
                *reinterpret_cast<short4v*>(vto + ((size_t)(b * KH_ + vh) * H_ + h) * T_ + t0r) = pv;
            }
        }
    }
}

// ---------------------------------------------------------------------------
// Barrier-free flash attention, S^T formulation, 32-s strips.
//   S^T = K·Q^T  (A=K frags, B=Q^T frags; both 16B-contiguous, dense per-head)
//   P stored row-major [t][s] via ds_write_b64 (4 consecutive s per reg quad)
//   O  = P·V     (A=P via ds_read_b128, B=V^T frags from vt)
// Per wave: 32 t-rows; strips of 32 s, PV immediately per strip.
// LDS: per-wave private 32x128 P buffer (8KB), 16B-atom XOR swizzle.
// ---------------------------------------------------------------------------
__global__ __launch_bounds__(256) void attn_kernel(
    const short* __restrict__ qp, const short* __restrict__ kp,
    const short* __restrict__ vtp, short* __restrict__ encp)
{
    __shared__ short ldsP[4 * 32 * 128];
    const int tid = threadIdx.x;
    const int w = tid >> 6, lane = tid & 63;
    const int quad = lane >> 4, l15 = lane & 15;
    const int widx = blockIdx.x * 4 + w;
    const int wt = 63 - (widx & 63);   // reversed: heavy waves dispatched first
    const int n  = (widx >> 6) & 31;
    const int b  = widx >> 11;
    const int kh = n >> 2;
    const int t0 = wt * 32;
    short* P = ldsP + w * (32 * 128);

    const short* qbase = qp  + (size_t)(b * N_  + n)  * T_ * H_;
    const short* kbase = kp  + (size_t)(b * KH_ + kh) * T_ * H_;
    const short* vbase = vtp + (size_t)(b * KH_ + kh) * H_ * T_;

    // Q^T B-frags, stationary: [k=h=32ks+8quad+j][n=t=16jc+l15]
    short8 qf[2][4];
#pragma unroll
    for (int jc = 0; jc < 2; jc++)
#pragma unroll
        for (int ks = 0; ks < 4; ks++)
            qf[jc][ks] = *reinterpret_cast<const short8*>(
                qbase + (size_t)(t0 + 16 * jc + l15) * H_ + ks * 32 + quad * 8);

    f32x4 o[2][8];     // O[m=t: 16jm+4quad+reg][n=h: 16jn+l15]
    const f32x4 zero4 = {0.f, 0.f, 0.f, 0.f};
#pragma unroll
    for (int jm = 0; jm < 2; jm++)
#pragma unroll
        for (int jn = 0; jn < 8; jn++) o[jm][jn] = zero4;
    float lsum[2] = {0.f, 0.f};   // l(t), t = 16jc + l15 (partial over this quad's s)

    for (int ss = 0; ss <= wt; ss++) {
        const int s0 = ss * 32;
        const int slot = (ss & 3) * 4;   // 16B-atom slot base in P (cycles 4 strips)

        // hoist V loads for this strip (independent of QK)
        short8 vb[8];
#pragma unroll
        for (int jn = 0; jn < 8; jn++)
            vb[jn] = *reinterpret_cast<const short8*>(
                vbase + (size_t)(16 * jn + l15) * T_ + s0 + quad * 8);

        // S^T: A=K[m=s=16jr2+l15][k=h], B=Q^T
        f32x4 s[2][2];
#pragma unroll
        for (int jr = 0; jr < 2; jr++)
#pragma unroll
            for (int jc = 0; jc < 2; jc++) s[jr][jc] = zero4;
#pragma unroll
        for (int ks = 0; ks < 4; ks++) {
            short8 kb[2];
#pragma unroll
            for (int jr = 0; jr < 2; jr++)
                kb[jr] = *reinterpret_cast<const short8*>(
                    kbase + (size_t)(s0 + 16 * jr + l15) * H_ + ks * 32 + quad * 8);
#pragma unroll
            for (int jr = 0; jr < 2; jr++)
#pragma unroll
                for (int jc = 0; jc < 2; jc++)
                    s[jr][jc] = __builtin_amdgcn_mfma_f32_16x16x32_bf16(kb[jr], qf[jc][ks], s[jr][jc], 0, 0, 0);
        }

        if (ss == wt) {  // diagonal strip: mask s_local > t_local
#pragma unroll
            for (int jr = 0; jr < 2; jr++)
#pragma unroll
                for (int jc = 0; jc < 2; jc++)
#pragma unroll
                    for (int reg = 0; reg < 4; reg++) {
                        int sl = 16 * jr + 4 * quad + reg;
                        int tl = 16 * jc + l15;
                        if (sl > tl) s[jr][jc][reg] = -1.0e30f;
                    }
        }

        // p = exp2(s), accumulate l, pack 4 consecutive s -> ds_write_b64
#pragma unroll
        for (int jr = 0; jr < 2; jr++)
#pragma unroll
            for (int jc = 0; jc < 2; jc++) {
                short4v pk;
#pragma unroll
                for (int reg = 0; reg < 4; reg++) {
                    float p = exp2f(s[jr][jc][reg]);
                    lsum[jc] += p;
                    pk[reg] = f2bf(p);
                }
                const int row = 16 * jc + l15;                       // t_local
                const int cc  = slot + 2 * jr + (quad >> 1);         // 16B atom
                const int hf  = quad & 1;                            // 8B half
                *reinterpret_cast<short4v*>(
                    &P[row * 128 + ((cc ^ l15) << 3) + (hf << 2)]) = pk;
            }
        asm volatile("s_waitcnt lgkmcnt(0)" ::: "memory");

        // O += P·V : A=P[m=t=16jm+l15][k=s_local=8quad+j], B=vb
#pragma unroll
        for (int jm = 0; jm < 2; jm++) {
            short8 pa = *reinterpret_cast<const short8*>(
                &P[(16 * jm + l15) * 128 + (((slot + quad) ^ l15) << 3)]);
#pragma unroll
            for (int jn = 0; jn < 8; jn++)
                o[jm][jn] = __builtin_amdgcn_mfma_f32_16x16x32_bf16(pa, vb[jn], o[jm][jn], 0, 0, 0);
        }
    }

    // epilogue: full l = quad-reduce; route to O's lane mapping; store bf16
#pragma unroll
    for (int jc = 0; jc < 2; jc++) {
        lsum[jc] += __shfl_xor(lsum[jc], 16, 64);
        lsum[jc] += __shfl_xor(lsum[jc], 32, 64);
    }
#pragma unroll
    for (int jm = 0; jm < 2; jm++)
#pragma unroll
        for (int reg = 0; reg < 4; reg++) {
            const float inv = 1.0f / __shfl(lsum[jm], 4 * quad + reg, 64);
            const int t = t0 + 16 * jm + 4 * quad + reg;
            const size_t base = (size_t)(b * T_ + t) * NH_ + n * H_;
#pragma unroll
            for (int jn = 0; jn < 8; jn++)
                encp[base + 16 * jn + l15] = f2bf(o[jm][jn][reg] * inv);
        }
}

// ---------------------------------------------------------------------------
// Output projection GEMM: out(BT,D) = enc(BT,NH) @ wot^T
// ---------------------------------------------------------------------------
__global__ __launch_bounds__(256) void out_gemm_kernel(
    const short* __restrict__ enc, const short* __restrict__ wot,
    float* __restrict__ out)
{
    __shared__ short As[128 * 32];
    __shared__ short Bs[128 * 32];
    const int d0 = blockIdx.x * 128;
    const int m0 = blockIdx.y * 128;
    const int tid = threadIdx.x;
    const int w = tid >> 6, lane = tid & 63;
    const int quad = lane >> 4, l15 = lane & 15;
    const int arow = lane >> 2, aslot = lane & 3;

    f32x4 acc[2][8];
    const f32x4 zero4 = {0.f, 0.f, 0.f, 0.f};
#pragma unroll
    for (int jr = 0; jr < 2; jr++)
#pragma unroll
        for (int jc = 0; jc < 8; jc++) acc[jr][jc] = zero4;

    for (int kt = 0; kt < NH_ / 32; kt++) {
        const int kk0 = kt * 32;
        __syncthreads();
#pragma unroll
        for (int i = 0; i < 2; i++) {
            const int ci = 2 * w + i;
            const int row = ci * 16 + arow;
            const int sl = aslot ^ (row & 3);
            gl_lds16(enc + (size_t)(m0 + row) * NH_ + kk0 + sl * 8, &As[ci * 512]);
            gl_lds16(wot + (size_t)(d0 + row) * NH_ + kk0 + sl * 8, &Bs[ci * 512]);
        }
        __syncthreads();
        short8 a[2], bq[8];
        const int fs = (quad ^ (l15 & 3)) * 8;
#pragma unroll
        for (int jr = 0; jr < 2; jr++)
            a[jr] = *reinterpret_cast<const short8*>(&As[(32 * w + 16 * jr + l15) * 32 + fs]);
#pragma unroll
        for (int jc = 0; jc < 8; jc++)
            bq[jc] = *reinterpret_cast<const short8*>(&Bs[(16 * jc + l15) * 32 + fs]);
#pragma unroll
        for (int jr = 0; jr < 2; jr++)
#pragma unroll
            for (int jc = 0; jc < 8; jc++)
                acc[jr][jc] = __builtin_amdgcn_mfma_f32_16x16x32_bf16(a[jr], bq[jc], acc[jr][jc], 0, 0, 0);
    }

#pragma unroll
    for (int jr = 0; jr < 2; jr++)
#pragma unroll
        for (int jc = 0; jc < 8; jc++)
#pragma unroll
            for (int reg = 0; reg < 4; reg++) {
                int r = m0 + 32 * w + 16 * jr + quad * 4 + reg;
                out[(size_t)r * D_ + d0 + 16 * jc + l15] = acc[jr][jc][reg];
            }
}

// ---------------------------------------------------------------------------
extern "C" void kernel_launch(void* const* d_in, const int* in_sizes, int n_in,
                              void* d_out, int out_size, void* d_ws, size_t ws_size,
                              hipStream_t stream)
{
    const float* x         = (const float*)d_in[0];
    const int*   positions = (const int*)d_in[1];
    const float* wq        = (const float*)d_in[3];
    const float* wkv       = (const float*)d_in[4];
    const float* wo        = (const float*)d_in[5];
    float* out = (float*)d_out;

    char* ws = (char*)d_ws;
    short* wqt  = (short*)(ws);                 // 33,554,432 B
    short* wkvt = (short*)(ws + 33554432);      // 16,777,216 B
    short* q    = (short*)(ws + 50331648);      // 33,554,432 B
    short* kx   = (short*)(ws + 83886080);      //  8,388,608 B
    short* vt   = (short*)(ws + 92274688);      //  8,388,608 B
    short* xbf  = (short*)(ws + 100663296);     // 33,554,432 B
    short* wot  = (short*)(ws + 100663296);     // alias of xbf
    short* enc  = (short*)(ws);                 // alias of wqt

    dim3 tb(32, 8);
    cast_x_kernel<<<dim3((BT_ * (size_t)D_) / 2048), dim3(256), 0, stream>>>(x, xbf);
    transpose_cast_kernel<<<dim3(H_/32, D_/32, N_),    tb, 0, stream>>>(wq,  wqt,  D_,  H_);
    transpose_cast_kernel<<<dim3(H_/32, D_/32, 2*KH_), tb, 0, stream>>>(wkv, wkvt, D_,  H_);

    qkv_gemm_kernel<<<dim3(48, BT_/128), dim3(256), 0, stream>>>(xbf, positions, wqt, wkvt, q, kx, vt);

    transpose_cast_kernel<<<dim3(D_/32, NH_/32, 1),    tb, 0, stream>>>(wo,  wot,  NH_, D_);

    attn_kernel<<<dim3((B_ * N_ * (T_/32)) / 4), dim3(256), 0, stream>>>(q, kx, vt, enc);
    out_gemm_kernel<<<dim3(D_/128, BT_/128), dim3(256), 0, stream>>>(enc, wot, out);
}

// Round 2
// 925.538 us; speedup vs baseline: 1.2264x; 1.2264x over previous
//
#include <hip/hip_runtime.h>

typedef short short8  __attribute__((ext_vector_type(8)));
typedef short short4v __attribute__((ext_vector_type(4)));
typedef float f32x4   __attribute__((ext_vector_type(4)));

#define B_   2
#define T_   2048
#define D_   4096
#define N_   32
#define KH_  8
#define H_   128
#define BT_  (B_*T_)
#define NH_  (N_*H_)

__device__ __forceinline__ short f2bf(float f) {
    unsigned u = __float_as_uint(f);
    u += 0x7fffu + ((u >> 16) & 1u);
    return (short)(u >> 16);
}

// global -> LDS async 16B copy; LDS dest = wave-uniform base + lane*16
__device__ __forceinline__ void gl_lds16(const short* g, short* l) {
    __builtin_amdgcn_global_load_lds(
        (const __attribute__((address_space(1))) void*)(g),
        (__attribute__((address_space(3))) void*)(l), 16, 0, 0);
}

// ---------------------------------------------------------------------------
// x fp32 -> bf16 flat cast
// ---------------------------------------------------------------------------
__global__ __launch_bounds__(256) void cast_x_kernel(const float* __restrict__ in,
                                                     short* __restrict__ out) {
    const size_t i = ((size_t)blockIdx.x * 256 + threadIdx.x) * 8;
    float4 v0 = *reinterpret_cast<const float4*>(in + i);
    float4 v1 = *reinterpret_cast<const float4*>(in + i + 4);
    short8 s;
    s[0] = f2bf(v0.x); s[1] = f2bf(v0.y); s[2] = f2bf(v0.z); s[3] = f2bf(v0.w);
    s[4] = f2bf(v1.x); s[5] = f2bf(v1.y); s[6] = f2bf(v1.z); s[7] = f2bf(v1.w);
    *reinterpret_cast<short8*>(out + i) = s;
}

// ---------------------------------------------------------------------------
// Transpose + cast: in (R,C) fp32 slices -> out (C,R) bf16 slices
// ---------------------------------------------------------------------------
__global__ void transpose_cast_kernel(const float* __restrict__ in,
                                      short* __restrict__ out, int R, int C) {
    __shared__ float tile[32][33];
    const long long slice = blockIdx.z;
    in  += slice * (long long)R * C;
    out += slice * (long long)R * C;
    const int c0 = blockIdx.x * 32, r0 = blockIdx.y * 32;
    const int tx = threadIdx.x, ty = threadIdx.y;
#pragma unroll
    for (int i = 0; i < 4; i++) {
        int r = r0 + ty + i * 8;
        tile[ty + i * 8][tx] = in[(long long)r * C + c0 + tx];
    }
    __syncthreads();
#pragma unroll
    for (int i = 0; i < 4; i++) {
        int cc = c0 + ty + i * 8;
        out[(long long)cc * R + r0 + tx] = f2bf(tile[tx][ty + i * 8]);
    }
}

// ---------------------------------------------------------------------------
// QKV projection GEMM (global_load_lds staging), fused RoPE epilogue.
// Outputs: q (B,N,T,H), k (B,KH,T,H)  [per-head dense], vt (B,KH,H,T).
// ---------------------------------------------------------------------------
__global__ __launch_bounds__(256) void qkv_gemm_kernel(
    const short* __restrict__ xb, const int* __restrict__ positions,
    const short* __restrict__ wqt, const short* __restrict__ wkvt,
    short* __restrict__ qo, short* __restrict__ ko, short* __restrict__ vto)
{
    __shared__ short As[128 * 32];
    __shared__ short Bs[128 * 32];
    const int hb  = blockIdx.x;
    const int m0  = blockIdx.y * 128;
    const int tid = threadIdx.x;
    const int w = tid >> 6, lane = tid & 63;
    const int quad = lane >> 4, l15 = lane & 15;
    const int arow = lane >> 2, aslot = lane & 3;

    const short* Bbase = (hb < 32) ? (wqt + (size_t)hb * H_ * D_)
                                   : (wkvt + (size_t)(hb - 32) * H_ * D_);

    f32x4 acc[2][8];
    const f32x4 zero4 = {0.f, 0.f, 0.f, 0.f};
#pragma unroll
    for (int jr = 0; jr < 2; jr++)
#pragma unroll
        for (int jc = 0; jc < 8; jc++) acc[jr][jc] = zero4;

    for (int kt = 0; kt < D_ / 32; kt++) {
        const int kk0 = kt * 32;
        __syncthreads();
#pragma unroll
        for (int i = 0; i < 2; i++) {
            const int ci = 2 * w + i;
            const int row = ci * 16 + arow;
            const int sl = aslot ^ (row & 3);
            gl_lds16(xb + (size_t)(m0 + row) * D_ + kk0 + sl * 8, &As[ci * 512]);
            gl_lds16(Bbase + (size_t)row * D_ + kk0 + sl * 8, &Bs[ci * 512]);
        }
        __syncthreads();
        short8 a[2], bq[8];
        const int fs = (quad ^ (l15 & 3)) * 8;
#pragma unroll
        for (int jr = 0; jr < 2; jr++)
            a[jr] = *reinterpret_cast<const short8*>(&As[(32 * w + 16 * jr + l15) * 32 + fs]);
#pragma unroll
        for (int jc = 0; jc < 8; jc++)
            bq[jc] = *reinterpret_cast<const short8*>(&Bs[(16 * jc + l15) * 32 + fs]);
#pragma unroll
        for (int jr = 0; jr < 2; jr++)
#pragma unroll
            for (int jc = 0; jc < 8; jc++)
                acc[jr][jc] = __builtin_amdgcn_mfma_f32_16x16x32_bf16(a[jr], bq[jc], acc[jr][jc], 0, 0, 0);
    }

    if (hb < 40) {
        // q or k: RoPE; q pre-scaled by H^-0.5 * log2e (fixed-max softmax)
        float qs;
        if (hb < 32) { qs = 0.08838834764831845f * 1.4426950408889634f; }
        else         { qs = 1.0f; }
#pragma unroll
        for (int jr = 0; jr < 2; jr++) {
#pragma unroll
            for (int reg = 0; reg < 4; reg++) {
                const int bt = m0 + 32 * w + 16 * jr + quad * 4 + reg;
                const int b = bt >> 11, t = bt & (T_ - 1);
                short* dst = (hb < 32)
                    ? qo + ((size_t)(b * N_ + hb) * T_ + t) * H_
                    : ko + ((size_t)(b * KH_ + (hb - 32)) * T_ + t) * H_;
                const float pos = (float)positions[bt];
#pragma unroll
                for (int jc = 0; jc < 4; jc++) {
                    const int h2 = 16 * jc + l15;
                    float inv_ts = exp2f((float)h2 * -0.20762050593048935f); // log2(10000)/64
                    float rev = pos * inv_ts * 0.15915494309189535f;
                    rev -= floorf(rev);
                    float sn, cs;
                    __sincosf(rev * 6.283185307179586f, &sn, &cs);
                    float x1 = acc[jr][jc][reg], x2 = acc[jr][jc + 4][reg];
                    dst[h2]      = f2bf((x1 * cs - x2 * sn) * qs);
                    dst[h2 + 64] = f2bf((x2 * cs + x1 * sn) * qs);
                }
            }
        }
    } else {
        // v: store transposed (B,KH,H,T)
        const int vh = hb - 40;
        const int b = m0 >> 11;
#pragma unroll
        for (int jr = 0; jr < 2; jr++) {
            const int t0r = (m0 - b * T_) + 32 * w + 16 * jr + quad * 4;
#pragma unroll
            for (int jc = 0; jc < 8; jc++) {
                const int h = 16 * jc + l15;
                short4v pv;
                pv[0] = f2bf(acc[jr][jc][0]); pv[1] = f2bf(acc[jr][jc][1]);
                pv[2] = f2bf(acc[jr][jc][2]); pv[3] = f2bf(acc[jr][jc][3]);
                *reinterpret_cast<short4v*>(vto + ((size_t)(b * KH_ + vh) * H_ + h) * T_ + t0r) = pv;
            }
        }
    }
}

// ---------------------------------------------------------------------------
// Barrier-free flash attention, S^T formulation, 32-s strips.
//   S^T = K·Q^T  (A=K frags, B=Q^T frags; both 16B-contiguous, dense per-head)
//   P stored row-major [t][s] via ds_write_b64 (4 consecutive s per reg quad)
//   O  = P·V     (A=P via ds_read_b128, B=V^T frags from vt)
// Causal pairing: each wave processes t-tiles {63-pr, pr} sequentially ->
// exactly 65 strips per wave, perfectly uniform across waves/CUs/XCDs.
// Cross-strip register prefetch: K[ss+1] issued after QK(ss) (hidden under
// exp2+LDS+PV), V[ss+1] issued after PV(ss) (hidden under next QK).
// LDS: per-wave private 32x128 P buffer (8KB), 16B-atom XOR swizzle.
// ---------------------------------------------------------------------------
__global__ __launch_bounds__(256) void attn_kernel(
    const short* __restrict__ qp, const short* __restrict__ kp,
    const short* __restrict__ vtp, short* __restrict__ encp)
{
    __shared__ short ldsP[4 * 32 * 128];
    const int tid = threadIdx.x;
    const int w = tid >> 6, lane = tid & 63;
    const int quad = lane >> 4, l15 = lane & 15;
    const int widx = blockIdx.x * 4 + w;
    const int pr = widx & 31;          // pair index: tiles {63-pr, pr}
    const int n  = (widx >> 5) & 31;
    const int b  = widx >> 10;
    const int kh = n >> 2;
    short* P = ldsP + w * (32 * 128);

    const short* qbase = qp  + (size_t)(b * N_  + n)  * T_ * H_;
    const short* kbase = kp  + (size_t)(b * KH_ + kh) * T_ * H_;
    const short* vbase = vtp + (size_t)(b * KH_ + kh) * H_ * T_;

    const f32x4 zero4 = {0.f, 0.f, 0.f, 0.f};

    for (int half = 0; half < 2; half++) {
        const int wt = half ? pr : (63 - pr);   // t-tile index; strips = wt+1
        const int t0 = wt * 32;

        // Q^T B-frags, stationary: [k=h=32ks+8quad+j][n=t=16jc+l15]
        short8 qf[2][4];
#pragma unroll
        for (int jc = 0; jc < 2; jc++)
#pragma unroll
            for (int ks = 0; ks < 4; ks++)
                qf[jc][ks] = *reinterpret_cast<const short8*>(
                    qbase + (size_t)(t0 + 16 * jc + l15) * H_ + ks * 32 + quad * 8);

        f32x4 o[2][8];     // O[m=t: 16jm+4quad+reg][n=h: 16jn+l15]
#pragma unroll
        for (int jm = 0; jm < 2; jm++)
#pragma unroll
            for (int jn = 0; jn < 8; jn++) o[jm][jn] = zero4;
        float lsum[2] = {0.f, 0.f};   // l(t), t = 16jc + l15 (partial over quad's s)

        // prologue: preload K/V for strip 0
        short8 kb[8];   // [2*ks+jr]
        short8 vb[8];
#pragma unroll
        for (int jn = 0; jn < 8; jn++)
            vb[jn] = *reinterpret_cast<const short8*>(
                vbase + (size_t)(16 * jn + l15) * T_ + quad * 8);
#pragma unroll
        for (int ks = 0; ks < 4; ks++)
#pragma unroll
            for (int jr = 0; jr < 2; jr++)
                kb[2 * ks + jr] = *reinterpret_cast<const short8*>(
                    kbase + (size_t)(16 * jr + l15) * H_ + ks * 32 + quad * 8);

        for (int ss = 0; ss <= wt; ss++) {
            const int s0 = ss * 32;
            const int slot = (ss & 3) * 4;   // 16B-atom slot base in P (cycles 4 strips)
            const int s0n = (ss < wt) ? s0 + 32 : 0;   // clamped prefetch strip

            // S^T: A=K[m=s=16jr+l15][k=h], B=Q^T  (K in registers from prefetch)
            f32x4 s[2][2];
#pragma unroll
            for (int jr = 0; jr < 2; jr++)
#pragma unroll
                for (int jc = 0; jc < 2; jc++) s[jr][jc] = zero4;
#pragma unroll
            for (int ks = 0; ks < 4; ks++)
#pragma unroll
                for (int jr = 0; jr < 2; jr++)
#pragma unroll
                    for (int jc = 0; jc < 2; jc++)
                        s[jr][jc] = __builtin_amdgcn_mfma_f32_16x16x32_bf16(kb[2 * ks + jr], qf[jc][ks], s[jr][jc], 0, 0, 0);

            // prefetch next strip's K (latency hides under exp2 + LDS + PV)
#pragma unroll
            for (int ks = 0; ks < 4; ks++)
#pragma unroll
                for (int jr = 0; jr < 2; jr++)
                    kb[2 * ks + jr] = *reinterpret_cast<const short8*>(
                        kbase + (size_t)(s0n + 16 * jr + l15) * H_ + ks * 32 + quad * 8);

            if (ss == wt) {  // diagonal strip: mask s_local > t_local
#pragma unroll
                for (int jr = 0; jr < 2; jr++)
#pragma unroll
                    for (int jc = 0; jc < 2; jc++)
#pragma unroll
                        for (int reg = 0; reg < 4; reg++) {
                            int sl = 16 * jr + 4 * quad + reg;
                            int tl = 16 * jc + l15;
                            if (sl > tl) s[jr][jc][reg] = -1.0e30f;
                        }
            }

            // p = exp2(s), accumulate l, pack 4 consecutive s -> ds_write_b64
#pragma unroll
            for (int jr = 0; jr < 2; jr++)
#pragma unroll
                for (int jc = 0; jc < 2; jc++) {
                    short4v pk;
#pragma unroll
                    for (int reg = 0; reg < 4; reg++) {
                        float p = exp2f(s[jr][jc][reg]);
                        lsum[jc] += p;
                        pk[reg] = f2bf(p);
                    }
                    const int row = 16 * jc + l15;                       // t_local
                    const int cc  = slot + 2 * jr + (quad >> 1);         // 16B atom
                    const int hf  = quad & 1;                            // 8B half
                    *reinterpret_cast<short4v*>(
                        &P[row * 128 + ((cc ^ l15) << 3) + (hf << 2)]) = pk;
                }
            asm volatile("s_waitcnt lgkmcnt(0)" ::: "memory");

            // O += P·V : A=P[m=t=16jm+l15][k=s_local=8quad+j], B=vb
#pragma unroll
            for (int jm = 0; jm < 2; jm++) {
                short8 pa = *reinterpret_cast<const short8*>(
                    &P[(16 * jm + l15) * 128 + (((slot + quad) ^ l15) << 3)]);
#pragma unroll
                for (int jn = 0; jn < 8; jn++)
                    o[jm][jn] = __builtin_amdgcn_mfma_f32_16x16x32_bf16(pa, vb[jn], o[jm][jn], 0, 0, 0);
            }

            // prefetch next strip's V (latency hides under next QK + exp2)
#pragma unroll
            for (int jn = 0; jn < 8; jn++)
                vb[jn] = *reinterpret_cast<const short8*>(
                    vbase + (size_t)(16 * jn + l15) * T_ + s0n + quad * 8);
        }

        // epilogue: full l = quad-reduce; route to O's lane mapping; store bf16
#pragma unroll
        for (int jc = 0; jc < 2; jc++) {
            lsum[jc] += __shfl_xor(lsum[jc], 16, 64);
            lsum[jc] += __shfl_xor(lsum[jc], 32, 64);
        }
#pragma unroll
        for (int jm = 0; jm < 2; jm++)
#pragma unroll
            for (int reg = 0; reg < 4; reg++) {
                const float inv = 1.0f / __shfl(lsum[jm], 4 * quad + reg, 64);
                const int t = t0 + 16 * jm + 4 * quad + reg;
                const size_t base = (size_t)(b * T_ + t) * NH_ + n * H_;
#pragma unroll
                for (int jn = 0; jn < 8; jn++)
                    encp[base + 16 * jn + l15] = f2bf(o[jm][jn][reg] * inv);
            }
    }
}

// ---------------------------------------------------------------------------
// Output projection GEMM: out(BT,D) = enc(BT,NH) @ wot^T
// ---------------------------------------------------------------------------
__global__ __launch_bounds__(256) void out_gemm_kernel(
    const short* __restrict__ enc, const short* __restrict__ wot,
    float* __restrict__ out)
{
    __shared__ short As[128 * 32];
    __shared__ short Bs[128 * 32];
    const int d0 = blockIdx.x * 128;
    const int m0 = blockIdx.y * 128;
    const int tid = threadIdx.x;
    const int w = tid >> 6, lane = tid & 63;
    const int quad = lane >> 4, l15 = lane & 15;
    const int arow = lane >> 2, aslot = lane & 3;

    f32x4 acc[2][8];
    const f32x4 zero4 = {0.f, 0.f, 0.f, 0.f};
#pragma unroll
    for (int jr = 0; jr < 2; jr++)
#pragma unroll
        for (int jc = 0; jc < 8; jc++) acc[jr][jc] = zero4;

    for (int kt = 0; kt < NH_ / 32; kt++) {
        const int kk0 = kt * 32;
        __syncthreads();
#pragma unroll
        for (int i = 0; i < 2; i++) {
            const int ci = 2 * w + i;
            const int row = ci * 16 + arow;
            const int sl = aslot ^ (row & 3);
            gl_lds16(enc + (size_t)(m0 + row) * NH_ + kk0 + sl * 8, &As[ci * 512]);
            gl_lds16(wot + (size_t)(d0 + row) * NH_ + kk0 + sl * 8, &Bs[ci * 512]);
        }
        __syncthreads();
        short8 a[2], bq[8];
        const int fs = (quad ^ (l15 & 3)) * 8;
#pragma unroll
        for (int jr = 0; jr < 2; jr++)
            a[jr] = *reinterpret_cast<const short8*>(&As[(32 * w + 16 * jr + l15) * 32 + fs]);
#pragma unroll
        for (int jc = 0; jc < 8; jc++)
            bq[jc] = *reinterpret_cast<const short8*>(&Bs[(16 * jc + l15) * 32 + fs]);
#pragma unroll
        for (int jr = 0; jr < 2; jr++)
#pragma unroll
            for (int jc = 0; jc < 8; jc++)
                acc[jr][jc] = __builtin_amdgcn_mfma_f32_16x16x32_bf16(a[jr], bq[jc], acc[jr][jc], 0, 0, 0);
    }

#pragma unroll
    for (int jr = 0; jr < 2; jr++)
#pragma unroll
        for (int jc = 0; jc < 8; jc++)
#pragma unroll
            for (int reg = 0; reg < 4; reg++) {
                int r = m0 + 32 * w + 16 * jr + quad * 4 + reg;
                out[(size_t)r * D_ + d0 + 16 * jc + l15] = acc[jr][jc][reg];
            }
}

// ---------------------------------------------------------------------------
extern "C" void kernel_launch(void* const* d_in, const int* in_sizes, int n_in,
                              void* d_out, int out_size, void* d_ws, size_t ws_size,
                              hipStream_t stream)
{
    const float* x         = (const float*)d_in[0];
    const int*   positions = (const int*)d_in[1];
    const float* wq        = (const float*)d_in[3];
    const float* wkv       = (const float*)d_in[4];
    const float* wo        = (const float*)d_in[5];
    float* out = (float*)d_out;

    char* ws = (char*)d_ws;
    short* wqt  = (short*)(ws);                 // 33,554,432 B
    short* wkvt = (short*)(ws + 33554432);      // 16,777,216 B
    short* q    = (short*)(ws + 50331648);      // 33,554,432 B
    short* kx   = (short*)(ws + 83886080);      //  8,388,608 B
    short* vt   = (short*)(ws + 92274688);      //  8,388,608 B
    short* xbf  = (short*)(ws + 100663296);     // 33,554,432 B
    short* wot  = (short*)(ws + 100663296);     // alias of xbf
    short* enc  = (short*)(ws);                 // alias of wqt

    dim3 tb(32, 8);
    cast_x_kernel<<<dim3((BT_ * (size_t)D_) / 2048), dim3(256), 0, stream>>>(x, xbf);
    transpose_cast_kernel<<<dim3(H_/32, D_/32, N_),    tb, 0, stream>>>(wq,  wqt,  D_,  H_);
    transpose_cast_kernel<<<dim3(H_/32, D_/32, 2*KH_), tb, 0, stream>>>(wkv, wkvt, D_,  H_);

    qkv_gemm_kernel<<<dim3(48, BT_/128), dim3(256), 0, stream>>>(xbf, positions, wqt, wkvt, q, kx, vt);

    transpose_cast_kernel<<<dim3(D_/32, NH_/32, 1),    tb, 0, stream>>>(wo,  wot,  NH_, D_);

    // 2048 uniform waves (65 strips each) in 512 blocks
    attn_kernel<<<dim3(512), dim3(256), 0, stream>>>(q, kx, vt, enc);
    out_gemm_kernel<<<dim3(D_/128, BT_/128), dim3(256), 0, stream>>>(enc, wot, out);
}

// Round 3
// 788.720 us; speedup vs baseline: 1.4392x; 1.1735x over previous
//
#include <hip/hip_runtime.h>

typedef short short8  __attribute__((ext_vector_type(8)));
typedef short short4v __attribute__((ext_vector_type(4)));
typedef float f32x4   __attribute__((ext_vector_type(4)));

#define B_   2
#define T_   2048
#define D_   4096
#define N_   32
#define KH_  8
#define H_   128
#define BT_  (B_*T_)
#define NH_  (N_*H_)
#define NTK  64          // K tiles of 64 (K = 4096 for both GEMMs)

__device__ __forceinline__ short f2bf(float f) {
    unsigned u = __float_as_uint(f);
    u += 0x7fffu + ((u >> 16) & 1u);
    return (short)(u >> 16);
}

// global -> LDS async 16B copy; LDS dest = wave-uniform base + lane*16
__device__ __forceinline__ void gl_lds16(const short* g, short* l) {
    __builtin_amdgcn_global_load_lds(
        (const __attribute__((address_space(1))) void*)(g),
        (__attribute__((address_space(3))) void*)(l), 16, 0, 0);
}

// ---------------------------------------------------------------------------
// x fp32 -> bf16 flat cast
// ---------------------------------------------------------------------------
__global__ __launch_bounds__(256) void cast_x_kernel(const float* __restrict__ in,
                                                     short* __restrict__ out) {
    const size_t i = ((size_t)blockIdx.x * 256 + threadIdx.x) * 8;
    float4 v0 = *reinterpret_cast<const float4*>(in + i);
    float4 v1 = *reinterpret_cast<const float4*>(in + i + 4);
    short8 s;
    s[0] = f2bf(v0.x); s[1] = f2bf(v0.y); s[2] = f2bf(v0.z); s[3] = f2bf(v0.w);
    s[4] = f2bf(v1.x); s[5] = f2bf(v1.y); s[6] = f2bf(v1.z); s[7] = f2bf(v1.w);
    *reinterpret_cast<short8*>(out + i) = s;
}

// ---------------------------------------------------------------------------
// Transpose + cast: in (R,C) fp32 slices -> out (C,R) bf16 slices
// ---------------------------------------------------------------------------
__global__ void transpose_cast_kernel(const float* __restrict__ in,
                                      short* __restrict__ out, int R, int C) {
    __shared__ float tile[32][33];
    const long long slice = blockIdx.z;
    in  += slice * (long long)R * C;
    out += slice * (long long)R * C;
    const int c0 = blockIdx.x * 32, r0 = blockIdx.y * 32;
    const int tx = threadIdx.x, ty = threadIdx.y;
#pragma unroll
    for (int i = 0; i < 4; i++) {
        int r = r0 + ty + i * 8;
        tile[ty + i * 8][tx] = in[(long long)r * C + c0 + tx];
    }
    __syncthreads();
#pragma unroll
    for (int i = 0; i < 4; i++) {
        int cc = c0 + ty + i * 8;
        out[(long long)cc * R + r0 + tx] = f2bf(tile[tx][ty + i * 8]);
    }
}

// ===========================================================================
// 256x256 8-phase GEMM core (BK=64, 512 threads, 8 waves as 4M x 2N).
// Per-wave C: 64 rows x 128 cols (jm 0..3, jn 0..7).
// LDS [buf][A/B][half][128x64 bf16], 128 KiB, XOR-atom swizzle (atom^(row&7));
// inverse-swizzled global source so linear global_load_lds lands swizzled.
// Phases per half-iter (compute buf=hf, tiles 2i/2i+1):
//   PA: vmcnt(4); bar; read a01+b03; stage B half0(tile 2i+1+hf -> buf hf^1); mfma jm01xjn03
//   PB: bar; read a23;               stage B half1 (same);                    mfma jm23xjn03
//   PC: bar; read b47;               stage A half0(tile 2i+2+hf -> buf hf);   mfma jm23xjn47
//   PD: bar;                         stage A half1 (same);                    mfma jm01xjn47
// Safety: B-halves of a tile dead after PC, A-halves after PB; every stage
// issues >=1 barrier after its slot's last read and drains (vmcnt(4)) before
// the slot's next read. 4-6 half-tiles in flight; never vmcnt(0) in loop.
// ===========================================================================

#define RD_A(cb, jm) {                                                          \
    const int rr_ = arow0 + (jm) * 16;                                          \
    a[jm][0] = *reinterpret_cast<const short8*>(&lds[cb][0][ah][rr_ * 64 + at0]); \
    a[jm][1] = *reinterpret_cast<const short8*>(&lds[cb][0][ah][rr_ * 64 + at1]); }

#define RD_B(cb, jn, jj) {                                                      \
    const int rb_ = (jn) * 16 + l15;                                            \
    b[jj][0] = *reinterpret_cast<const short8*>(&lds[cb][1][wc][rb_ * 64 + at0]); \
    b[jj][1] = *reinterpret_cast<const short8*>(&lds[cb][1][wc][rb_ * 64 + at1]); }

#define STAGE(ab, G, rowbase, sb, h, kt_) {                                     \
    int kt_c = (kt_); if (kt_c > NTK - 1) kt_c = NTK - 1;                       \
    const short* gsrc_ = (G) + (size_t)((rowbase) + (h) * 128 + srow) * 4096    \
                             + kt_c * 64 + sca * 8;                             \
    gl_lds16(gsrc_,            &lds[sb][ab][h][(2 * w) * 512]);                 \
    gl_lds16(gsrc_ + 8 * 4096, &lds[sb][ab][h][(2 * w) * 512 + 512]); }

#define MFMA_Q(JM0, JN0)                                                        \
    __builtin_amdgcn_s_setprio(1);                                              \
    _Pragma("unroll")                                                           \
    for (int jm_ = 0; jm_ < 2; ++jm_)                                           \
    _Pragma("unroll")                                                           \
    for (int jn_ = 0; jn_ < 4; ++jn_)                                           \
    _Pragma("unroll")                                                           \
    for (int ks_ = 0; ks_ < 2; ++ks_)                                           \
        acc[(JM0) + jm_][(JN0) + jn_] = __builtin_amdgcn_mfma_f32_16x16x32_bf16( \
            a[(JM0) + jm_][ks_], b[jn_][ks_], acc[(JM0) + jm_][(JN0) + jn_], 0, 0, 0); \
    __builtin_amdgcn_s_setprio(0);

#define GEMM8_PRO_AND_LOOP(Ap, Bp, m0, n0)                                      \
    f32x4 acc[4][8];                                                            \
    {const f32x4 z_ = {0.f,0.f,0.f,0.f};                                        \
    _Pragma("unroll") for (int jm_=0;jm_<4;++jm_)                               \
    _Pragma("unroll") for (int jn_=0;jn_<8;++jn_) acc[jm_][jn_]=z_;}            \
    short8 a[4][2], b[4][2];                                                    \
    STAGE(0, Ap, m0, 0, 0, 0); STAGE(0, Ap, m0, 0, 1, 0);                       \
    STAGE(1, Bp, n0, 0, 0, 0); STAGE(1, Bp, n0, 0, 1, 0);                       \
    STAGE(0, Ap, m0, 1, 0, 1); STAGE(0, Ap, m0, 1, 1, 1);                       \
    for (int i = 0; i < NTK / 2; ++i) {                                         \
        _Pragma("unroll")                                                       \
        for (int hf = 0; hf < 2; ++hf) {                                        \
            const int cb = hf, sbB = hf ^ 1;                                    \
            const int tB = 2 * i + 1 + hf;                                      \
            const int tA = 2 * i + 2 + hf;                                      \
            /* PA */                                                            \
            asm volatile("s_waitcnt vmcnt(4)" ::: "memory");                    \
            __builtin_amdgcn_s_barrier();                                       \
            RD_A(cb, 0); RD_A(cb, 1);                                           \
            RD_B(cb, 0, 0); RD_B(cb, 1, 1); RD_B(cb, 2, 2); RD_B(cb, 3, 3);     \
            STAGE(1, Bp, n0, sbB, 0, tB);                                       \
            MFMA_Q(0, 0);                                                       \
            /* PB */                                                            \
            __builtin_amdgcn_s_barrier();                                       \
            RD_A(cb, 2); RD_A(cb, 3);                                           \
            STAGE(1, Bp, n0, sbB, 1, tB);                                       \
            MFMA_Q(2, 0);                                                       \
            /* PC */                                                            \
            __builtin_amdgcn_s_barrier();                                       \
            RD_B(cb, 4, 0); RD_B(cb, 5, 1); RD_B(cb, 6, 2); RD_B(cb, 7, 3);     \
            STAGE(0, Ap, m0, hf, 0, tA);                                        \
            MFMA_Q(2, 4);                                                       \
            /* PD */                                                            \
            __builtin_amdgcn_s_barrier();                                       \
            STAGE(0, Ap, m0, hf, 1, tA);                                        \
            MFMA_Q(0, 4);                                                       \
        }                                                                       \
    }                                                                           \
    asm volatile("s_waitcnt vmcnt(0)" ::: "memory");

// ---------------------------------------------------------------------------
// QKV projection GEMM, 8-phase. B = [wqt|wkvt] contiguous (6144 x 4096 bf16).
// Block n-tile = 2 heads; wave wc owns one full head (128 cols) -> RoPE pairs
// (h, h+64) stay in-wave. Outputs: q (B,N,T,H), k (B,KH,T,H), vt (B,KH,H,T).
// ---------------------------------------------------------------------------
__global__ __launch_bounds__(512, 2) void qkv_gemm8_kernel(
    const short* __restrict__ xb, const int* __restrict__ positions,
    const short* __restrict__ wqt,
    short* __restrict__ qo, short* __restrict__ ko, short* __restrict__ vto)
{
    __shared__ short lds[2][2][2][8192];
    const int tid = threadIdx.x;
    const int w = tid >> 6, lane = tid & 63;
    const int quad = lane >> 4, l15 = lane & 15;
    const int wr = w >> 1, wc = w & 1;
    const int ah = wr >> 1;
    const int arow0 = (wr & 1) * 64 + l15;
    const int sw = l15 & 7;
    const int at0 = (quad ^ sw) * 8;
    const int at1 = ((4 + quad) ^ sw) * 8;
    const int srow = 16 * w + (lane >> 3);
    const int sca = (lane & 7) ^ (lane >> 3);
    const int m0 = blockIdx.y * 256;
    const int n0 = blockIdx.x * 256;

    GEMM8_PRO_AND_LOOP(xb, wqt, m0, n0)

    const int head = 2 * blockIdx.x + wc;
    if (head < 40) {
        const float qs = (head < 32) ? (0.08838834764831845f * 1.4426950408889634f) : 1.0f;
#pragma unroll
        for (int jm = 0; jm < 4; ++jm) {
#pragma unroll
            for (int reg = 0; reg < 4; ++reg) {
                const int bt = m0 + wr * 64 + jm * 16 + quad * 4 + reg;
                const int bb = bt >> 11, t = bt & (T_ - 1);
                short* dst = (head < 32)
                    ? qo + ((size_t)(bb * N_ + head) * T_ + t) * H_
                    : ko + ((size_t)(bb * KH_ + (head - 32)) * T_ + t) * H_;
                const float pos = (float)positions[bt];
#pragma unroll
                for (int jn = 0; jn < 4; ++jn) {
                    const int h2 = jn * 16 + l15;
                    float inv_ts = exp2f((float)h2 * -0.20762050593048935f); // log2(10000)/64
                    float rev = pos * inv_ts * 0.15915494309189535f;
                    rev -= floorf(rev);
                    float sn, cs;
                    __sincosf(rev * 6.283185307179586f, &sn, &cs);
                    float x1 = acc[jm][jn][reg], x2 = acc[jm][jn + 4][reg];
                    dst[h2]      = f2bf((x1 * cs - x2 * sn) * qs);
                    dst[h2 + 64] = f2bf((x2 * cs + x1 * sn) * qs);
                }
            }
        }
    } else {
        const int vh = head - 40;
        const int bb = m0 >> 11;
        const int tl0 = (m0 & (T_ - 1)) + wr * 64;
#pragma unroll
        for (int jm = 0; jm < 4; ++jm) {
            const int t0r = tl0 + jm * 16 + quad * 4;
#pragma unroll
            for (int jn = 0; jn < 8; ++jn) {
                const int h = jn * 16 + l15;
                short4v pv;
                pv[0] = f2bf(acc[jm][jn][0]); pv[1] = f2bf(acc[jm][jn][1]);
                pv[2] = f2bf(acc[jm][jn][2]); pv[3] = f2bf(acc[jm][jn][3]);
                *reinterpret_cast<short4v*>(vto + ((size_t)(bb * KH_ + vh) * H_ + h) * T_ + t0r) = pv;
            }
        }
    }
}

// ---------------------------------------------------------------------------
// Output projection GEMM, 8-phase: out(BT,D) = enc(BT,NH) @ wot^T
// ---------------------------------------------------------------------------
__global__ __launch_bounds__(512, 2) void out_gemm8_kernel(
    const short* __restrict__ enc, const short* __restrict__ wot,
    float* __restrict__ out)
{
    __shared__ short lds[2][2][2][8192];
    const int tid = threadIdx.x;
    const int w = tid >> 6, lane = tid & 63;
    const int quad = lane >> 4, l15 = lane & 15;
    const int wr = w >> 1, wc = w & 1;
    const int ah = wr >> 1;
    const int arow0 = (wr & 1) * 64 + l15;
    const int sw = l15 & 7;
    const int at0 = (quad ^ sw) * 8;
    const int at1 = ((4 + quad) ^ sw) * 8;
    const int srow = 16 * w + (lane >> 3);
    const int sca = (lane & 7) ^ (lane >> 3);
    const int m0 = blockIdx.y * 256;
    const int n0 = blockIdx.x * 256;

    GEMM8_PRO_AND_LOOP(enc, wot, m0, n0)

#pragma unroll
    for (int jm = 0; jm < 4; ++jm)
#pragma unroll
        for (int jn = 0; jn < 8; ++jn)
#pragma unroll
            for (int reg = 0; reg < 4; ++reg) {
                const int r = m0 + wr * 64 + jm * 16 + quad * 4 + reg;
                out[(size_t)r * D_ + n0 + wc * 128 + jn * 16 + l15] = acc[jm][jn][reg];
            }
}

// ---------------------------------------------------------------------------
// Barrier-free flash attention, S^T formulation, 32-s strips. (unchanged)
// ---------------------------------------------------------------------------
__global__ __launch_bounds__(256) void attn_kernel(
    const short* __restrict__ qp, const short* __restrict__ kp,
    const short* __restrict__ vtp, short* __restrict__ encp)
{
    __shared__ short ldsP[4 * 32 * 128];
    const int tid = threadIdx.x;
    const int w = tid >> 6, lane = tid & 63;
    const int quad = lane >> 4, l15 = lane & 15;
    const int widx = blockIdx.x * 4 + w;
    const int pr = widx & 31;          // pair index: tiles {63-pr, pr}
    const int n  = (widx >> 5) & 31;
    const int b  = widx >> 10;
    const int kh = n >> 2;
    short* P = ldsP + w * (32 * 128);

    const short* qbase = qp  + (size_t)(b * N_  + n)  * T_ * H_;
    const short* kbase = kp  + (size_t)(b * KH_ + kh) * T_ * H_;
    const short* vbase = vtp + (size_t)(b * KH_ + kh) * H_ * T_;

    const f32x4 zero4 = {0.f, 0.f, 0.f, 0.f};

    for (int half = 0; half < 2; half++) {
        const int wt = half ? pr : (63 - pr);   // t-tile index; strips = wt+1
        const int t0 = wt * 32;

        // Q^T B-frags, stationary: [k=h=32ks+8quad+j][n=t=16jc+l15]
        short8 qf[2][4];
#pragma unroll
        for (int jc = 0; jc < 2; jc++)
#pragma unroll
            for (int ks = 0; ks < 4; ks++)
                qf[jc][ks] = *reinterpret_cast<const short8*>(
                    qbase + (size_t)(t0 + 16 * jc + l15) * H_ + ks * 32 + quad * 8);

        f32x4 o[2][8];     // O[m=t: 16jm+4quad+reg][n=h: 16jn+l15]
#pragma unroll
        for (int jm = 0; jm < 2; jm++)
#pragma unroll
            for (int jn = 0; jn < 8; jn++) o[jm][jn] = zero4;
        float lsum[2] = {0.f, 0.f};   // l(t), t = 16jc + l15 (partial over quad's s)

        // prologue: preload K/V for strip 0
        short8 kb[8];   // [2*ks+jr]
        short8 vb[8];
#pragma unroll
        for (int jn = 0; jn < 8; jn++)
            vb[jn] = *reinterpret_cast<const short8*>(
                vbase + (size_t)(16 * jn + l15) * T_ + quad * 8);
#pragma unroll
        for (int ks = 0; ks < 4; ks++)
#pragma unroll
            for (int jr = 0; jr < 2; jr++)
                kb[2 * ks + jr] = *reinterpret_cast<const short8*>(
                    kbase + (size_t)(16 * jr + l15) * H_ + ks * 32 + quad * 8);

        for (int ss = 0; ss <= wt; ss++) {
            const int s0 = ss * 32;
            const int slot = (ss & 3) * 4;   // 16B-atom slot base in P (cycles 4 strips)
            const int s0n = (ss < wt) ? s0 + 32 : 0;   // clamped prefetch strip

            // S^T: A=K[m=s=16jr+l15][k=h], B=Q^T  (K in registers from prefetch)
            f32x4 s[2][2];
#pragma unroll
            for (int jr = 0; jr < 2; jr++)
#pragma unroll
                for (int jc = 0; jc < 2; jc++) s[jr][jc] = zero4;
#pragma unroll
            for (int ks = 0; ks < 4; ks++)
#pragma unroll
                for (int jr = 0; jr < 2; jr++)
#pragma unroll
                    for (int jc = 0; jc < 2; jc++)
                        s[jr][jc] = __builtin_amdgcn_mfma_f32_16x16x32_bf16(kb[2 * ks + jr], qf[jc][ks], s[jr][jc], 0, 0, 0);

            // prefetch next strip's K (latency hides under exp2 + LDS + PV)
#pragma unroll
            for (int ks = 0; ks < 4; ks++)
#pragma unroll
                for (int jr = 0; jr < 2; jr++)
                    kb[2 * ks + jr] = *reinterpret_cast<const short8*>(
                        kbase + (size_t)(s0n + 16 * jr + l15) * H_ + ks * 32 + quad * 8);

            if (ss == wt) {  // diagonal strip: mask s_local > t_local
#pragma unroll
                for (int jr = 0; jr < 2; jr++)
#pragma unroll
                    for (int jc = 0; jc < 2; jc++)
#pragma unroll
                        for (int reg = 0; reg < 4; reg++) {
                            int sl = 16 * jr + 4 * quad + reg;
                            int tl = 16 * jc + l15;
                            if (sl > tl) s[jr][jc][reg] = -1.0e30f;
                        }
            }

            // p = exp2(s), accumulate l, pack 4 consecutive s -> ds_write_b64
#pragma unroll
            for (int jr = 0; jr < 2; jr++)
#pragma unroll
                for (int jc = 0; jc < 2; jc++) {
                    short4v pk;
#pragma unroll
                    for (int reg = 0; reg < 4; reg++) {
                        float p = exp2f(s[jr][jc][reg]);
                        lsum[jc] += p;
                        pk[reg] = f2bf(p);
                    }
                    const int row = 16 * jc + l15;                       // t_local
                    const int cc  = slot + 2 * jr + (quad >> 1);         // 16B atom
                    const int hf  = quad & 1;                            // 8B half
                    *reinterpret_cast<short4v*>(
                        &P[row * 128 + ((cc ^ l15) << 3) + (hf << 2)]) = pk;
                }
            asm volatile("s_waitcnt lgkmcnt(0)" ::: "memory");

            // O += P·V : A=P[m=t=16jm+l15][k=s_local=8quad+j], B=vb
#pragma unroll
            for (int jm = 0; jm < 2; jm++) {
                short8 pa = *reinterpret_cast<const short8*>(
                    &P[(16 * jm + l15) * 128 + (((slot + quad) ^ l15) << 3)]);
#pragma unroll
                for (int jn = 0; jn < 8; jn++)
                    o[jm][jn] = __builtin_amdgcn_mfma_f32_16x16x32_bf16(pa, vb[jn], o[jm][jn], 0, 0, 0);
            }

            // prefetch next strip's V (latency hides under next QK + exp2)
#pragma unroll
            for (int jn = 0; jn < 8; jn++)
                vb[jn] = *reinterpret_cast<const short8*>(
                    vbase + (size_t)(16 * jn + l15) * T_ + s0n + quad * 8);
        }

        // epilogue: full l = quad-reduce; route to O's lane mapping; store bf16
#pragma unroll
        for (int jc = 0; jc < 2; jc++) {
            lsum[jc] += __shfl_xor(lsum[jc], 16, 64);
            lsum[jc] += __shfl_xor(lsum[jc], 32, 64);
        }
#pragma unroll
        for (int jm = 0; jm < 2; jm++)
#pragma unroll
            for (int reg = 0; reg < 4; reg++) {
                const float inv = 1.0f / __shfl(lsum[jm], 4 * quad + reg, 64);
                const int t = t0 + 16 * jm + 4 * quad + reg;
                const size_t base = (size_t)(b * T_ + t) * NH_ + n * H_;
#pragma unroll
                for (int jn = 0; jn < 8; jn++)
                    encp[base + 16 * jn + l15] = f2bf(o[jm][jn][reg] * inv);
            }
    }
}

// ---------------------------------------------------------------------------
extern "C" void kernel_launch(void* const* d_in, const int* in_sizes, int n_in,
                              void* d_out, int out_size, void* d_ws, size_t ws_size,
                              hipStream_t stream)
{
    const float* x         = (const float*)d_in[0];
    const int*   positions = (const int*)d_in[1];
    const float* wq        = (const float*)d_in[3];
    const float* wkv       = (const float*)d_in[4];
    const float* wo        = (const float*)d_in[5];
    float* out = (float*)d_out;

    char* ws = (char*)d_ws;
    short* wqt  = (short*)(ws);                 // 33,554,432 B  (wkvt contiguous after)
    short* wkvt = (short*)(ws + 33554432);      // 16,777,216 B
    short* q    = (short*)(ws + 50331648);      // 33,554,432 B
    short* kx   = (short*)(ws + 83886080);      //  8,388,608 B
    short* vt   = (short*)(ws + 92274688);      //  8,388,608 B
    short* xbf  = (short*)(ws + 100663296);     // 33,554,432 B
    short* wot  = (short*)(ws + 100663296);     // alias of xbf
    short* enc  = (short*)(ws);                 // alias of wqt

    dim3 tb(32, 8);
    cast_x_kernel<<<dim3((BT_ * (size_t)D_) / 2048), dim3(256), 0, stream>>>(x, xbf);
    transpose_cast_kernel<<<dim3(H_/32, D_/32, N_),    tb, 0, stream>>>(wq,  wqt,  D_,  H_);
    transpose_cast_kernel<<<dim3(H_/32, D_/32, 2*KH_), tb, 0, stream>>>(wkv, wkvt, D_,  H_);

    // 8-phase 256^2 GEMM: grid (n-tiles = 6144/256 = 24, m-tiles = 4096/256 = 16)
    qkv_gemm8_kernel<<<dim3(24, 16), dim3(512), 0, stream>>>(xbf, positions, wqt, q, kx, vt);

    transpose_cast_kernel<<<dim3(D_/32, NH_/32, 1),    tb, 0, stream>>>(wo,  wot,  NH_, D_);

    // 2048 uniform waves (65 strips each) in 512 blocks
    attn_kernel<<<dim3(512), dim3(256), 0, stream>>>(q, kx, vt, enc);

    out_gemm8_kernel<<<dim3(16, 16), dim3(512), 0, stream>>>(enc, wot, out);
}